// Round 2
// baseline (247.029 us; speedup 1.0000x reference)
//
#include <hip/hip_runtime.h>

#define NPIX (128 * 128)   // pixels per channel plane
#define CH 64
#define RMID 16            // CHANNELS / RED
#define GROUPS 32
#define KK 9

// Block = 256 threads = 4 waves. Each block owns 64 consecutive pixels
// (half an image row -> hq, bq are block-uniform). Wave q handles:
//   phase 1: t rows [4q, 4q+4) for its lane's pixel  (conv1, no FLOP dup)
//   phase 2: groups [8q, 8q+8)                        (conv2 + involution)
// t[16] shared through LDS with stride 17 (coprime 32 -> conflict-free).
__global__ __launch_bounds__(256, 6) void involution_fused(
    const float* __restrict__ x,
    const float* __restrict__ w1,
    const float* __restrict__ b1,
    const float* __restrict__ prelu_a,
    const float* __restrict__ w2,
    const float* __restrict__ b2,
    float* __restrict__ out)
{
    __shared__ float tl[64 * 17];

    const int px = threadIdx.x & 63;   // lane = pixel within block
    const int q  = threadIdx.x >> 6;   // wave id 0..3

    // block-uniform decomposition (from blockIdx only -> provably uniform)
    const int blk  = blockIdx.x;           // 0..2047
    const int bq   = blk >> 8;             // batch
    const int hq   = (blk >> 1) & 127;     // row
    const int w0   = (blk & 1) * 64;       // column base of this half-row
    const int wq   = w0 + px;
    const int puni = hq * 128 + w0;        // uniform part of in-plane index
    const int p    = puni + px;

    const float* xb = x + (size_t)bq * CH * NPIX;

    // ---- Phase 1: conv1 rows [4q, 4q+4) for pixel p ----
    float t4[4];
#pragma unroll
    for (int r = 0; r < 4; ++r) t4[r] = b1[4 * q + r];

#pragma unroll 8
    for (int c = 0; c < CH; ++c) {
        const float xv = xb[(size_t)c * NPIX + p];
#pragma unroll
        for (int r = 0; r < 4; ++r)
            t4[r] = fmaf(w1[(4 * q + r) * CH + c], xv, t4[r]);  // w1 wave-uniform -> s_load
    }
    const float a = prelu_a[0];
#pragma unroll
    for (int r = 0; r < 4; ++r) {
        float v = t4[r];
        v = (v >= 0.f) ? v : a * v;
        tl[px * 17 + 4 * q + r] = v;
    }
    __syncthreads();

    // ---- Phase 2: groups [8q, 8q+8) ----
    float tr[RMID];
#pragma unroll
    for (int r = 0; r < RMID; ++r) tr[r] = tl[px * 17 + r];

    // tap offsets (clamped) + masks folded into generated weights
    int   pofs[KK];
    float msk[KK];
#pragma unroll
    for (int i = 0; i < 3; ++i) {
#pragma unroll
        for (int j = 0; j < 3; ++j) {
            const int k  = i * 3 + j;
            const int dh = i - 1, dw = j - 1;
            const bool okk = ((unsigned)(hq + dh) < 128u) && ((unsigned)(wq + dw) < 128u);
            pofs[k] = okk ? (px + dh * 128 + dw) : px;   // clamped -> always in-bounds
            msk[k]  = okk ? 1.f : 0.f;
        }
    }

    float* ob = out + (size_t)bq * CH * NPIX;

    for (int gi = 0; gi < 8; ++gi) {
        const int g = q * 8 + gi;                         // wave-uniform group id

        // -- software pipeline: issue the 18 stencil loads first --
        const float* xp0 = xb + (size_t)(2 * g) * NPIX + puni;  // uniform base + v-offset
        const float* xp1 = xp0 + NPIX;
        float p0[KK], p1[KK];
#pragma unroll
        for (int k = 0; k < KK; ++k) {
            p0[k] = xp0[pofs[k]];
            p1[k] = xp1[pofs[k]];
        }

        // -- conv2: 9 weights from tr[16] (covers the load latency) --
        float wg[KK];
#pragma unroll
        for (int k = 0; k < KK; ++k) {
            float acc = b2[g * KK + k];
            const float* w2r = w2 + (g * KK + k) * RMID;  // wave-uniform -> s_load
#pragma unroll
            for (int r = 0; r < RMID; ++r)
                acc = fmaf(w2r[r], tr[r], acc);
            wg[k] = acc * msk[k];                          // border taps -> weight 0
        }

        // -- combine --
        float o0 = 0.f, o1 = 0.f;
#pragma unroll
        for (int k = 0; k < KK; ++k) {
            o0 = fmaf(wg[k], p0[k], o0);
            o1 = fmaf(wg[k], p1[k], o1);
        }
        ob[(size_t)(2 * g)     * NPIX + p] = o0;
        ob[(size_t)(2 * g + 1) * NPIX + p] = o1;
    }
}

extern "C" void kernel_launch(void* const* d_in, const int* in_sizes, int n_in,
                              void* d_out, int out_size, void* d_ws, size_t ws_size,
                              hipStream_t stream)
{
    const float* x  = (const float*)d_in[0];
    const float* w1 = (const float*)d_in[1];
    const float* b1 = (const float*)d_in[2];
    const float* pa = (const float*)d_in[3];
    const float* w2 = (const float*)d_in[4];
    const float* b2 = (const float*)d_in[5];
    float* out = (float*)d_out;

    const int nblocks = 8 * 128 * 2;   // batch * rows * half-rows = 2048
    hipLaunchKernelGGL(involution_fused, dim3(nblocks), dim3(256), 0, stream,
                       x, w1, b1, pa, w2, b2, out);
}

// Round 3
// 133.034 us; speedup vs baseline: 1.8569x; 1.8569x over previous
//
#include <hip/hip_runtime.h>

#define NPIX (128 * 128)   // pixels per channel plane
#define CH 64
#define RMID 16            // CHANNELS / RED
#define GROUPS 32
#define KK 9

// Block = 512 threads = 8 waves, covering 2 full rows (256 pixels).
//   px    = tid & 255  : pixel within the 2-row strip
//   layer = tid >> 8   : 0 -> groups 0..15, 1 -> groups 16..31
// layer is constant within each wave => group id g is wave-uniform =>
// readfirstlane(g) gives scalar channel-plane bases: stencil loads are
// s[base] + per-lane byte offset (precomputed once), no per-load VALU math.
// conv1 split: layer 0 computes t rows 0..7, layer 1 rows 8..15; shared
// through LDS (stride 17, coprime with 32 banks).
__global__ __launch_bounds__(512, 4) void involution_fused(
    const float* __restrict__ x,
    const float* __restrict__ w1,
    const float* __restrict__ b1,
    const float* __restrict__ prelu_a,
    const float* __restrict__ w2,
    const float* __restrict__ b2,
    float* __restrict__ out)
{
    __shared__ float tl[256 * 17];

    const int px    = threadIdx.x & 255;
    const int layer = threadIdx.x >> 8;

    const int blk = blockIdx.x;            // 0..511
    const int bq  = blk >> 6;              // batch
    const int hp  = blk & 63;              // row pair
    const int hq  = 2 * hp + (px >> 7);
    const int wq  = px & 127;
    const int p   = hq * 128 + wq;

    const float* xb = x + (size_t)bq * CH * NPIX;

    // ---- Phase 1: conv1 rows [8*layer, 8*layer+8) for pixel p ----
    const int r0 = 8 * layer;
    float t8[8];
#pragma unroll
    for (int r = 0; r < 8; ++r) t8[r] = b1[r0 + r];

#pragma unroll 8
    for (int c = 0; c < CH; ++c) {
        const float xv = xb[(size_t)c * NPIX + p];
#pragma unroll
        for (int r = 0; r < 8; ++r)
            t8[r] = fmaf(w1[(r0 + r) * CH + c], xv, t8[r]);   // w1 uniform -> s_load
    }
    const float a = prelu_a[0];
#pragma unroll
    for (int r = 0; r < 8; ++r) {
        const float v = t8[r];
        tl[px * 17 + r0 + r] = (v >= 0.f) ? v : a * v;
    }
    __syncthreads();

    // ---- Phase 2: groups [16*layer, 16*layer+16) ----
    float tr[RMID];
#pragma unroll
    for (int r = 0; r < RMID; ++r) tr[r] = tl[px * 17 + r];

    // per-lane clamped BYTE offsets within a channel plane + border masks
    int   qb[KK];
    float msk[KK];
#pragma unroll
    for (int i = 0; i < 3; ++i) {
#pragma unroll
        for (int j = 0; j < 3; ++j) {
            const int k  = i * 3 + j;
            const int dh = i - 1, dw = j - 1;
            const bool okk = ((unsigned)(hq + dh) < 128u) && ((unsigned)(wq + dw) < 128u);
            qb[k]  = 4 * (okk ? (p + dh * 128 + dw) : p);   // clamped -> in-bounds
            msk[k] = okk ? 1.f : 0.f;                        // folded into weights
        }
    }

    const char* xbc = (const char*)xb;
    char*       obc = (char*)(out + (size_t)bq * CH * NPIX);
    const int   pb  = 4 * p;

#pragma unroll 4
    for (int gi = 0; gi < 16; ++gi) {
        const int g = __builtin_amdgcn_readfirstlane(16 * layer + gi);  // scalar group id

        const char* c0 = xbc + (size_t)(2 * g) * NPIX * 4;  // scalar plane bases
        const char* c1 = c0 + (size_t)NPIX * 4;

        // -- batch the 18 stencil loads (s-base + v byte-offset) --
        float p0[KK], p1[KK];
#pragma unroll
        for (int k = 0; k < KK; ++k) {
            p0[k] = *(const float*)(c0 + qb[k]);
            p1[k] = *(const float*)(c1 + qb[k]);
        }

        // -- conv2: 9 weights from tr[16] (covers the load latency) --
        float wg[KK];
#pragma unroll
        for (int k = 0; k < KK; ++k) {
            float acc = b2[g * KK + k];
            const float* w2r = w2 + (g * KK + k) * RMID;     // scalar -> s_load
#pragma unroll
            for (int r = 0; r < RMID; ++r)
                acc = fmaf(w2r[r], tr[r], acc);
            wg[k] = acc * msk[k];                            // border taps -> weight 0
        }

        // -- combine + store --
        float o0 = 0.f, o1 = 0.f;
#pragma unroll
        for (int k = 0; k < KK; ++k) {
            o0 = fmaf(wg[k], p0[k], o0);
            o1 = fmaf(wg[k], p1[k], o1);
        }
        *(float*)(obc + (size_t)(2 * g)     * NPIX * 4 + pb) = o0;
        *(float*)(obc + (size_t)(2 * g + 1) * NPIX * 4 + pb) = o1;
    }
}

extern "C" void kernel_launch(void* const* d_in, const int* in_sizes, int n_in,
                              void* d_out, int out_size, void* d_ws, size_t ws_size,
                              hipStream_t stream)
{
    const float* x  = (const float*)d_in[0];
    const float* w1 = (const float*)d_in[1];
    const float* b1 = (const float*)d_in[2];
    const float* pa = (const float*)d_in[3];
    const float* w2 = (const float*)d_in[4];
    const float* b2 = (const float*)d_in[5];
    float* out = (float*)d_out;

    const int nblocks = 8 * 64;   // batch * row-pairs = 512 blocks of 512 threads
    hipLaunchKernelGGL(involution_fused, dim3(nblocks), dim3(512), 0, stream,
                       x, w1, b1, pa, w2, b2, out);
}